// Round 3
// baseline (2613.572 us; speedup 1.0000x reference)
//
#include <hip/hip_runtime.h>

// GRU scan: T=128, N=1024, H=512, I=64.
// ONE persistent (non-cooperative) kernel: 256 blocks x 256 threads, ~1 block/CU,
// all blocks co-resident by capacity (>=256 VGPR -> 1 wave/SIMD -> 1 block/CU).
// Each wave owns a 32-row x 16-col output tile for the entire scan and holds ALL
// its weight fragments in registers (54 half8 = 216 regs, mostly AGPR-allocated).
// KEY dataflow fact: block (rg,cg) writes h16 rows rg*32..+31 and reads ONLY those
// same 32 rows -> h16 communication is confined to the 8 blocks of a row-group.
// Step boundary = per-row-group 8-arrival spin barrier on an agent-scope atomic
// counter + acquire fence (invalidates stale L1/L2 lines; per-XCD L2s are not
// cross-coherent). h16 stores are 64-bit agent-scope atomic stores (write-through
// past the non-coherent caches). Numerics identical to the passing round-1 kernel.

#define T_STEPS 128
#define NBATCH  1024
#define HDIM    512
#define IDIM    64
#define KTOT    576
#define NGROUPS 32
#define CTR_STRIDE 64   // ints between per-group counters (256 B apart)

typedef _Float16 half8  __attribute__((ext_vector_type(8)));
typedef _Float16 half4  __attribute__((ext_vector_type(4)));
typedef float    floatx4 __attribute__((ext_vector_type(4)));

__global__ void prep_w_kernel(const float* __restrict__ Whh,
                              const float* __restrict__ Wih,
                              _Float16* __restrict__ W16,
                              int* __restrict__ cnt) {
    if (blockIdx.x == 0) {
        for (int i = threadIdx.x; i < NGROUPS * CTR_STRIDE; i += 256) cnt[i] = 0;
    }
    int idx = blockIdx.x * 256 + threadIdx.x;
    if (idx >= 1536 * KTOT) return;
    int c = idx / KTOT;
    int k = idx - c * KTOT;
    float v = (k < HDIM) ? Whh[c * HDIM + k] : Wih[c * IDIM + (k - HDIM)];
    W16[idx] = (_Float16)v;
}

// x16m[t][n][i] = fp16( pact[t][n][i] * masks[t*N+n] )
__global__ void prep_x_kernel(const float* __restrict__ pact,
                              const float* __restrict__ masks,
                              _Float16* __restrict__ x16) {
    int idx = blockIdx.x * 256 + threadIdx.x;
    if (idx >= T_STEPS * NBATCH * IDIM / 4) return;
    int e = idx * 4;
    float mk = masks[e >> 6];
    floatx4 v = *(const floatx4*)(pact + e);
    half4 h;
    h[0] = (_Float16)(v.x * mk);
    h[1] = (_Float16)(v.y * mk);
    h[2] = (_Float16)(v.z * mk);
    h[3] = (_Float16)(v.w * mk);
    *(half4*)(x16 + e) = h;
}

// h16m[n][h] = fp16( hxs[n][h] * masks[n] )   (step 0)
__global__ void prep_h_kernel(const float* __restrict__ hxs,
                              const float* __restrict__ masks,
                              _Float16* __restrict__ h16) {
    int idx = blockIdx.x * 256 + threadIdx.x;
    if (idx >= NBATCH * HDIM / 4) return;
    int e = idx * 4;
    float mk = masks[e >> 9];
    floatx4 v = *(const floatx4*)(hxs + e);
    half4 h;
    h[0] = (_Float16)(v.x * mk);
    h[1] = (_Float16)(v.y * mk);
    h[2] = (_Float16)(v.z * mk);
    h[3] = (_Float16)(v.w * mk);
    *(half4*)(h16 + e) = h;
}

__device__ __forceinline__ float sigmoidf_(float x) {
    return 1.0f / (1.0f + __expf(-x));
}

#define MFMA16(a, b, c) __builtin_amdgcn_mfma_f32_16x16x32_f16((a), (b), (c), 0, 0, 0)

__global__ __launch_bounds__(256, 1)
void gru_scan_kernel(const float* __restrict__ hxs,
                     const _Float16* __restrict__ x16all,
                     const float* __restrict__ masks,
                     const _Float16* __restrict__ W16,
                     const float* __restrict__ b_ih,
                     const float* __restrict__ b_hh,
                     float* __restrict__ out,
                     _Float16* h16a,          // no restrict: cross-block shared
                     _Float16* h16b,
                     int* cnt) {
    const int tid  = threadIdx.x;
    const int wave = tid >> 6;          // 0..3 -> 16-col subtile
    const int lane = tid & 63;
    const int n16  = lane & 15;
    const int q    = lane >> 4;
    const int rg   = (int)blockIdx.x >> 3;                   // row group 0..31
    const int rowbase = rg * 32;
    const int colw    = ((int)blockIdx.x & 7) * 64 + wave * 16;
    const int c0      = colw + q * 4;
    int* const ctr = cnt + rg * CTR_STRIDE;

    // ---- preload ALL weight fragments into registers (fixed across steps)
    half8 wreg[18][3];
#pragma unroll
    for (int kt = 0; kt < 18; ++kt)
#pragma unroll
        for (int g = 0; g < 3; ++g)
            wreg[kt][g] = *(const half8*)(W16 +
                (size_t)(g * HDIM + colw + n16) * KTOT + kt * 32 + q * 8);

    // ---- biases in registers
    floatx4 br4, bz4, bin4, bhn4;
    {
        floatx4 a = *(const floatx4*)(b_ih + c0);
        floatx4 b = *(const floatx4*)(b_hh + c0);
        br4 = a + b;
        a = *(const floatx4*)(b_ih + HDIM + c0);
        b = *(const floatx4*)(b_hh + HDIM + c0);
        bz4 = a + b;
        bin4 = *(const floatx4*)(b_ih + 2 * HDIM + c0);
        bhn4 = *(const floatx4*)(b_hh + 2 * HDIM + c0);
    }

    const size_t hO0 = (size_t)(rowbase + n16) * HDIM + q * 8;
    const size_t hO1 = hO0 + (size_t)16 * HDIM;
    const size_t xO0 = (size_t)(rowbase + n16) * IDIM + q * 8;
    const size_t xO1 = xO0 + (size_t)16 * IDIM;
    const int i0 = rowbase + n16;
    const int i1 = i0 + 16;
    const size_t oO0 = (size_t)i0 * HDIM + c0;
    const size_t oO1 = (size_t)i1 * HDIM + c0;

    const _Float16* hcur = h16a;
    _Float16* hnxt = h16b;
    const float* hprev32 = hxs;

#pragma unroll 1
    for (int t = 0; t < T_STEPS; ++t) {
        floatx4 accr0  = (floatx4){0.f, 0.f, 0.f, 0.f};
        floatx4 accr1  = (floatx4){0.f, 0.f, 0.f, 0.f};
        floatx4 accz0  = (floatx4){0.f, 0.f, 0.f, 0.f};
        floatx4 accz1  = (floatx4){0.f, 0.f, 0.f, 0.f};
        floatx4 acchn0 = (floatx4){0.f, 0.f, 0.f, 0.f};
        floatx4 acchn1 = (floatx4){0.f, 0.f, 0.f, 0.f};
        floatx4 accin0 = (floatx4){0.f, 0.f, 0.f, 0.f};
        floatx4 accin1 = (floatx4){0.f, 0.f, 0.f, 0.f};

        // K = 0..511 : h part
#pragma unroll
        for (int kt = 0; kt < 16; ++kt) {
            half8 h0 = *(const half8*)(hcur + hO0 + kt * 32);
            half8 h1 = *(const half8*)(hcur + hO1 + kt * 32);
            accr0  = MFMA16(wreg[kt][0], h0, accr0);
            accz0  = MFMA16(wreg[kt][1], h0, accz0);
            acchn0 = MFMA16(wreg[kt][2], h0, acchn0);
            accr1  = MFMA16(wreg[kt][0], h1, accr1);
            accz1  = MFMA16(wreg[kt][1], h1, accz1);
            acchn1 = MFMA16(wreg[kt][2], h1, acchn1);
        }
        // K = 512..575 : x part
        const _Float16* xt = x16all + (size_t)t * NBATCH * IDIM;
#pragma unroll
        for (int kk = 0; kk < 2; ++kk) {
            half8 x0 = *(const half8*)(xt + xO0 + kk * 32);
            half8 x1 = *(const half8*)(xt + xO1 + kk * 32);
            accr0  = MFMA16(wreg[16 + kk][0], x0, accr0);
            accz0  = MFMA16(wreg[16 + kk][1], x0, accz0);
            accin0 = MFMA16(wreg[16 + kk][2], x0, accin0);
            accr1  = MFMA16(wreg[16 + kk][0], x1, accr1);
            accz1  = MFMA16(wreg[16 + kk][1], x1, accz1);
            accin1 = MFMA16(wreg[16 + kk][2], x1, accin1);
        }

        // ---- epilogue (D layout: col c = c0 + r contiguous, row i = slab*16 + n16)
        float* out_x = out + (size_t)t * NBATCH * HDIM;
        {
            const float mtv = masks[(size_t)t * NBATCH + i0];
            floatx4 hp = *(const floatx4*)(hprev32 + oO0);
            floatx4 hv;
#pragma unroll
            for (int r = 0; r < 4; ++r) {
                float rg_ = sigmoidf_(accr0[r] + br4[r]);
                float zg = sigmoidf_(accz0[r] + bz4[r]);
                float ng = tanhf(accin0[r] + bin4[r] + rg_ * (acchn0[r] + bhn4[r]));
                hv[r] = (1.0f - zg) * ng + zg * (hp[r] * mtv);
            }
            *(floatx4*)(out_x + oO0) = hv;
            if (t == T_STEPS - 1) {
                *(floatx4*)(out + (size_t)T_STEPS * NBATCH * HDIM + oO0) = hv;
            } else {
                const float mnv = masks[(size_t)(t + 1) * NBATCH + i0];
                half4 hh;
                hh[0] = (_Float16)(hv[0] * mnv);
                hh[1] = (_Float16)(hv[1] * mnv);
                hh[2] = (_Float16)(hv[2] * mnv);
                hh[3] = (_Float16)(hv[3] * mnv);
                __hip_atomic_store((unsigned long long*)(hnxt + oO0),
                                   __builtin_bit_cast(unsigned long long, hh),
                                   __ATOMIC_RELAXED, __HIP_MEMORY_SCOPE_AGENT);
            }
        }
        {
            const float mtv = masks[(size_t)t * NBATCH + i1];
            floatx4 hp = *(const floatx4*)(hprev32 + oO1);
            floatx4 hv;
#pragma unroll
            for (int r = 0; r < 4; ++r) {
                float rg_ = sigmoidf_(accr1[r] + br4[r]);
                float zg = sigmoidf_(accz1[r] + bz4[r]);
                float ng = tanhf(accin1[r] + bin4[r] + rg_ * (acchn1[r] + bhn4[r]));
                hv[r] = (1.0f - zg) * ng + zg * (hp[r] * mtv);
            }
            *(floatx4*)(out_x + oO1) = hv;
            if (t == T_STEPS - 1) {
                *(floatx4*)(out + (size_t)T_STEPS * NBATCH * HDIM + oO1) = hv;
            } else {
                const float mnv = masks[(size_t)(t + 1) * NBATCH + i1];
                half4 hh;
                hh[0] = (_Float16)(hv[0] * mnv);
                hh[1] = (_Float16)(hv[1] * mnv);
                hh[2] = (_Float16)(hv[2] * mnv);
                hh[3] = (_Float16)(hv[3] * mnv);
                __hip_atomic_store((unsigned long long*)(hnxt + oO1),
                                   __builtin_bit_cast(unsigned long long, hh),
                                   __ATOMIC_RELAXED, __HIP_MEMORY_SCOPE_AGENT);
            }
        }

        hprev32 = out_x;
        { const _Float16* tmp = hcur; hcur = hnxt; hnxt = (_Float16*)tmp; }

        if (t != T_STEPS - 1) {
            // ---- per-row-group barrier (8 sibling blocks share h16 rows)
            __syncthreads();   // compiler drains vmcnt(0) for every wave here
            if (tid == 0) {
                __hip_atomic_fetch_add(ctr, 1, __ATOMIC_RELEASE,
                                       __HIP_MEMORY_SCOPE_AGENT);
                const int target = 8 * (t + 1);
                while (__hip_atomic_load(ctr, __ATOMIC_RELAXED,
                                         __HIP_MEMORY_SCOPE_AGENT) < target) {
                    __builtin_amdgcn_s_sleep(1);
                }
            }
            __syncthreads();
            // acquire: invalidate stale L1/L2 lines before reading siblings' h16
            __builtin_amdgcn_fence(__ATOMIC_ACQUIRE, "agent");
        }
    }
}

extern "C" void kernel_launch(void* const* d_in, const int* in_sizes, int n_in,
                              void* d_out, int out_size, void* d_ws, size_t ws_size,
                              hipStream_t stream) {
    const float* hxs   = (const float*)d_in[0];
    // d_in[1] = gru_init: dead code in the reference, unused
    const float* masks = (const float*)d_in[2];
    const float* pact  = (const float*)d_in[3];
    const float* W_ih  = (const float*)d_in[4];
    const float* W_hh  = (const float*)d_in[5];
    const float* b_ih  = (const float*)d_in[6];
    const float* b_hh  = (const float*)d_in[7];
    float* out = (float*)d_out;

    // workspace layout (fp16): W16 | x16m | h16m[2] | counters
    _Float16* W16  = (_Float16*)d_ws;                                  // 1536*576
    _Float16* x16  = W16 + 1536 * KTOT;                                // T*N*I
    _Float16* h16a = x16 + (size_t)T_STEPS * NBATCH * IDIM;            // N*H
    _Float16* h16b = h16a + (size_t)NBATCH * HDIM;                     // N*H
    int* cnt       = (int*)(h16b + (size_t)NBATCH * HDIM);             // 32*64 ints

    const int wtot = 1536 * KTOT;
    prep_w_kernel<<<(wtot + 255) / 256, 256, 0, stream>>>(W_hh, W_ih, W16, cnt);
    const int xtot = T_STEPS * NBATCH * IDIM / 4;
    prep_x_kernel<<<(xtot + 255) / 256, 256, 0, stream>>>(pact, masks, x16);
    const int htot = NBATCH * HDIM / 4;
    prep_h_kernel<<<(htot + 255) / 256, 256, 0, stream>>>(hxs, masks, h16a);

    gru_scan_kernel<<<256, 256, 0, stream>>>(
        hxs, x16, masks, W16, b_ih, b_hh, out, h16a, h16b, cnt);
}